// Round 10
// baseline (693.343 us; speedup 1.0000x reference)
//
#include <hip/hip_runtime.h>
#include <stdint.h>

// GLA block for MI355X (gfx950).
// B=8 S=2048 D=1024 H=4 DK=128 DV=256 CHUNK=64 (32 chunks), MLP_H=4096.
// R10: gemm256 wait schedule aligned to the verified m201 template: counted
// vmcnt(4) ONLY at P4/P8 (was vmcnt at P1/P4/P5/P8) — removes 2 exposed stall
// points per iteration. Derivation: end-P4 confirms through P2's stage (all of
// t1); end-P8 confirms through P6 (all of t0+2); invariant 4 loads outstanding.
// Everything else identical to R9 (passed, 692 us, absmax 0.078).

typedef unsigned short u16t;
typedef __attribute__((ext_vector_type(8))) short bf16x8;
typedef __attribute__((ext_vector_type(4))) float f32x4;
typedef __attribute__((ext_vector_type(4))) unsigned short u16x4;

__device__ __forceinline__ float bf2f(unsigned short u){ union{unsigned int i; float f;} v; v.i=((unsigned int)u)<<16; return v.f; }
__device__ __forceinline__ unsigned short f2bf(float f){ union{unsigned int i; float f;} v; v.f=f; unsigned int r=v.i+0x7FFFu+((v.i>>16)&1u); return (unsigned short)(r>>16); }
__device__ __forceinline__ f32x4 cvt4(u16x4 u){ f32x4 r; r[0]=bf2f(u[0]); r[1]=bf2f(u[1]); r[2]=bf2f(u[2]); r[3]=bf2f(u[3]); return r; }

// fast tanh-GELU (native exp2/rcp); |err| vs exact-erf gelu ~3e-4.
__device__ __forceinline__ float gelu_f(float t){
  const float t3 = t*t*t;
  const float y = 2.3021183f*t + 0.10295465f*t3;
  const float e = __builtin_amdgcn_exp2f(y);
  return t - t*__builtin_amdgcn_rcpf(e + 1.f);
}

__device__ __forceinline__ void gload_lds16(const unsigned short* g, unsigned short* l)
{
  __builtin_amdgcn_global_load_lds(
      (const __attribute__((address_space(1))) unsigned int*)g,
      (__attribute__((address_space(3))) unsigned int*)l,
      16, 0, 0);
}

// ---------------- merged transpose f32 [Kin][N] -> bf16 [N][Kin], 7 weights ----------------
__global__ void k_transpose_multi(const float* __restrict__ Wq, const float* __restrict__ Wk,
                                  const float* __restrict__ Wv, const float* __restrict__ Wg,
                                  const float* __restrict__ Wo, const float* __restrict__ W1,
                                  const float* __restrict__ W2,
                                  unsigned short* __restrict__ WPT, unsigned short* __restrict__ WOT,
                                  unsigned short* __restrict__ W1T, unsigned short* __restrict__ W2T)
{
  __shared__ float tile[32][33];
  int bid = blockIdx.x;
  const float* src; unsigned short* dst; int Kin, N, nx;
  if      (bid < 512)  { src=Wq; dst=WPT;                          Kin=1024; N=512;  nx=16;  }
  else if (bid < 1024) { src=Wk; dst=WPT+(size_t)512*1024;         Kin=1024; N=512;  nx=16;  bid-=512;  }
  else if (bid < 2048) { src=Wv; dst=WPT+(size_t)1024*1024;        Kin=1024; N=1024; nx=32;  bid-=1024; }
  else if (bid < 3072) { src=Wg; dst=WPT+(size_t)2048*1024;        Kin=1024; N=1024; nx=32;  bid-=2048; }
  else if (bid < 4096) { src=Wo; dst=WOT;                          Kin=1024; N=1024; nx=32;  bid-=3072; }
  else if (bid < 8192) { src=W1; dst=W1T;                          Kin=1024; N=4096; nx=128; bid-=4096; }
  else                 { src=W2; dst=W2T;                          Kin=4096; N=1024; nx=32;  bid-=8192; }
  const int n0 = (bid % nx)*32, k0 = (bid / nx)*32;
  const int tx = threadIdx.x, ty = threadIdx.y;
  #pragma unroll
  for (int i = 0; i < 4; ++i)
    tile[ty + i*8][tx] = src[(size_t)(k0 + ty + i*8)*N + n0 + tx];
  __syncthreads();
  #pragma unroll
  for (int i = 0; i < 4; ++i)
    dst[(size_t)(n0 + ty + i*8)*Kin + k0 + tx] = f2bf(tile[tx][ty + i*8]);
}

// ---------------- Wgk = Wgk1[1024,16] @ Wgk2[16,512] -> bf16 transposed rows [512][1024] ----------------
__global__ void k_wgk(const float* __restrict__ Wgk1, const float* __restrict__ Wgk2, unsigned short* __restrict__ dstT)
{
  const int idx = blockIdx.x*256 + threadIdx.x;
  const int i = idx & 1023, j = idx >> 10;
  float s = 0.f;
  #pragma unroll
  for (int r = 0; r < 16; ++r) s += Wgk1[i*16 + r] * Wgk2[r*512 + j];
  dstT[(size_t)j*1024 + i] = f2bf(s);
}

// ---------------- V/K transpose: proj v-cols -> VT[bh][256][2048]; kt -> KTT[bh][128][2048] ----------------
__global__ void k_vtrans(const unsigned short* __restrict__ proj, const unsigned short* __restrict__ kt,
                         unsigned short* __restrict__ vtg, unsigned short* __restrict__ ktt)
{
  __shared__ unsigned short tile[32][33];
  const int tt = blockIdx.x, zz = blockIdx.y, bh = blockIdx.z;
  const int b = bh >> 2, h = bh & 3;
  const int tx = threadIdx.x, ty = threadIdx.y;
  if (zz < 8) {
    const int dvt = zz;
    #pragma unroll
    for (int i = 0; i < 4; ++i)
      tile[ty + i*8][tx] = proj[((size_t)b*2048 + tt*32 + ty + i*8)*3584 + 1024 + h*256 + dvt*32 + tx];
    __syncthreads();
    #pragma unroll
    for (int i = 0; i < 4; ++i)
      vtg[((size_t)bh*256 + dvt*32 + ty + i*8)*2048 + tt*32 + tx] = tile[tx][ty + i*8];
  } else {
    const int dkt = zz - 8;
    #pragma unroll
    for (int i = 0; i < 4; ++i)
      tile[ty + i*8][tx] = kt[((size_t)bh*2048 + tt*32 + ty + i*8)*128 + dkt*32 + tx];
    __syncthreads();
    #pragma unroll
    for (int i = 0; i < 4; ++i)
      ktt[((size_t)bh*128 + dkt*32 + ty + i*8)*2048 + tt*32 + tx] = tile[tx][ty + i*8];
  }
}

// ---------------- LayerNorm row=1024, f32 in -> bf16 out ----------------
__global__ __launch_bounds__(256) void k_layernorm(const float* __restrict__ x, const float* __restrict__ g,
                                                   const float* __restrict__ b, unsigned short* __restrict__ out)
{
  const int row = blockIdx.x, tid = threadIdx.x;
  const float4 xv = *(const float4*)&x[(size_t)row*1024 + tid*4];
  float s  = xv.x + xv.y + xv.z + xv.w;
  float sq = xv.x*xv.x + xv.y*xv.y + xv.z*xv.z + xv.w*xv.w;
  #pragma unroll
  for (int o = 32; o > 0; o >>= 1) { s += __shfl_xor(s, o); sq += __shfl_xor(sq, o); }
  __shared__ float red[8];
  const int w = tid >> 6;
  if ((tid & 63) == 0) { red[w] = s; red[4 + w] = sq; }
  __syncthreads();
  s  = red[0] + red[1] + red[2] + red[3];
  sq = red[4] + red[5] + red[6] + red[7];
  const float mu = s * (1.f/1024.f);
  const float var = sq * (1.f/1024.f) - mu*mu;
  const float rs = rsqrtf(var + 1e-5f);
  float xe[4] = {xv.x, xv.y, xv.z, xv.w};
  u16x4 o4;
  #pragma unroll
  for (int i = 0; i < 4; ++i) {
    const int c = tid*4 + i;
    o4[i] = f2bf((xe[i] - mu) * rs * g[c] + b[c]);
  }
  *(u16x4*)&out[(size_t)row*1024 + tid*4] = o4;
}

// ---------------- 256x256 8-phase bf16 MFMA GEMM: C = A[M,K] @ Bt[N,K]^T ----------------
template<int EPI>
__global__ __launch_bounds__(512, 2)
void gemm256(const unsigned short* __restrict__ A, const unsigned short* __restrict__ Bt,
             int N, int K,
             float* outF, unsigned short* outH,
             const float* resid, const float* bias)
{
  __shared__ __align__(16) unsigned short lds[65536];
  const int tid = threadIdx.x;
  const int lane = tid & 63, w = tid >> 6;
  const int wr = w >> 2, wc = w & 3;
  const int l15 = lane & 15, lq = lane >> 4;

  const int nwg = gridDim.x * gridDim.y;
  const int bid = blockIdx.y * gridDim.x + blockIdx.x;
  const int q = nwg >> 3, r = nwg & 7;
  const int xcd = bid & 7, lid = bid >> 3;
  const int sw = (xcd < r ? xcd*(q+1) : r*(q+1) + (xcd - r)*q) + lid;
  const int row0 = (sw / gridDim.x) * 256;
  const int col0 = (sw % gridDim.x) * 256;

  const int rA_ = tid >> 3;
  const int cswz = 8 * ((tid & 7) ^ (rA_ & 7));
  const unsigned short* baseA[2][2];
  const unsigned short* baseB[2][2];
  #pragma unroll
  for (int h = 0; h < 2; ++h)
    #pragma unroll
    for (int L = 0; L < 2; ++L) {
      baseA[h][L] = A  + (size_t)(row0 + h*128 + L*64 + rA_) * K + cswz;
      baseB[h][L] = Bt + (size_t)(col0 + h*128 + L*64 + rA_) * K + cswz;
    }

  const int NT = K >> 6;
  const int NI = NT >> 1;

  f32x4 acc[8][4];
  #pragma unroll
  for (int m = 0; m < 8; ++m)
    #pragma unroll
    for (int n = 0; n < 4; ++n) { acc[m][n][0]=0.f; acc[m][n][1]=0.f; acc[m][n][2]=0.f; acc[m][n][3]=0.f; }

  bf16x8 af[4][2];
  bf16x8 bfr[2][2][2];

  #define STAGE(CH, T)                                                         \
    {                                                                          \
      const int tt = ((T) < NT) ? (T) : (T) - 2;                               \
      const int dbase = (tt & 1) * 32768 + (CH) * 8192;                        \
      const int ktt2 = tt << 6;                                                \
      _Pragma("unroll")                                                        \
      for (int L = 0; L < 2; ++L) {                                            \
        const unsigned short* gp =                                             \
            ((CH) < 2 ? baseA[(CH) & 1][L] : baseB[(CH) & 1][L]) + ktt2;       \
        gload_lds16(gp, (unsigned short*)&lds[dbase + L*4096 + w*512]);        \
      }                                                                        \
    }

  #define DS_A(CB)                                                             \
    { _Pragma("unroll")                                                        \
      for (int mm = 0; mm < 4; ++mm) {                                         \
        const int rl = wr*64 + mm*16 + l15;                                    \
        const int co = (l15 & 7) * 8;                                          \
        af[mm][0] = *(const bf16x8*)&lds[(CB) + rl*64 + ((lq*8) ^ co)];        \
        af[mm][1] = *(const bf16x8*)&lds[(CB) + rl*64 + ((32 + lq*8) ^ co)];   \
      } }

  #define DS_B(CB, QN)                                                         \
    { _Pragma("unroll")                                                        \
      for (int nn = 0; nn < 2; ++nn) {                                         \
        const int rl = wc*32 + nn*16 + l15;                                    \
        const int co = (l15 & 7) * 8;                                          \
        bfr[QN][nn][0] = *(const bf16x8*)&lds[(CB) + (2+(QN))*8192 + rl*64 + ((lq*8) ^ co)];      \
        bfr[QN][nn][1] = *(const bf16x8*)&lds[(CB) + (2+(QN))*8192 + rl*64 + ((32 + lq*8) ^ co)]; \
      } }

  #define PRE_MFMA()                                                           \
    { __builtin_amdgcn_s_barrier();                                            \
      asm volatile("s_waitcnt lgkmcnt(0)" ::: "memory");                       \
      __builtin_amdgcn_sched_barrier(0); }

  #define MMA(QM, QN)                                                          \
    { __builtin_amdgcn_s_setprio(1);                                           \
      _Pragma("unroll")                                                        \
      for (int mm = 0; mm < 4; ++mm)                                           \
        _Pragma("unroll")                                                      \
        for (int nn = 0; nn < 2; ++nn) {                                       \
          acc[(QM)*4+mm][(QN)*2+nn] = __builtin_amdgcn_mfma_f32_16x16x32_bf16( \
              af[mm][0], bfr[QN][nn][0], acc[(QM)*4+mm][(QN)*2+nn], 0, 0, 0);  \
          acc[(QM)*4+mm][(QN)*2+nn] = __builtin_amdgcn_mfma_f32_16x16x32_bf16( \
              af[mm][1], bfr[QN][nn][1], acc[(QM)*4+mm][(QN)*2+nn], 0, 0, 0);  \
        }                                                                      \
      __builtin_amdgcn_s_setprio(0); }

  #define POSTW(VN)                                                            \
    { asm volatile("s_waitcnt vmcnt(" #VN ")" ::: "memory");                   \
      __builtin_amdgcn_sched_barrier(0);                                       \
      __builtin_amdgcn_s_barrier(); }

  #define POSTN() { __builtin_amdgcn_s_barrier(); }

  // prologue: tile0 all 4 chunks + t1's Ah0/Bh0; confirm tile0 (vmcnt(4) leaves
  // Ah0(1),Bh0(1) in flight — steady-state invariant).
  STAGE(0, 0); STAGE(2, 0); STAGE(1, 0); STAGE(3, 0); STAGE(0, 1); STAGE(2, 1);
  asm volatile("s_waitcnt vmcnt(4)" ::: "memory");
  __builtin_amdgcn_sched_barrier(0);
  __builtin_amdgcn_s_barrier();

  for (int i = 0; i < NI; ++i) {
    const int t0 = 2*i, t1 = 2*i + 1;
    // P1..P3: all reads confirmed by previous iteration's P8 vmcnt(4)
    DS_A(0); DS_B(0, 0); STAGE(1, t1);
    PRE_MFMA(); MMA(0, 0); POSTN();
    DS_B(0, 1); STAGE(3, t1);
    PRE_MFMA(); MMA(0, 1); POSTN();
    DS_A(8192); STAGE(0, t0 + 2);
    PRE_MFMA(); MMA(1, 0); POSTN();
    // P4: confirm through P2's stage -> all of t1 landed (4 left outstanding)
    STAGE(2, t0 + 2);
    PRE_MFMA(); MMA(1, 1); POSTW(4);
    DS_A(32768); DS_B(32768, 0); STAGE(1, t0 + 2);
    PRE_MFMA(); MMA(0, 0); POSTN();
    DS_B(32768, 1); STAGE(3, t0 + 2);
    PRE_MFMA(); MMA(0, 1); POSTN();
    DS_A(32768 + 8192); STAGE(0, t1 + 2);
    PRE_MFMA(); MMA(1, 0); POSTN();
    // P8: confirm through P6's stage -> all of t0+2 landed (4 left outstanding)
    STAGE(2, t1 + 2);
    PRE_MFMA(); MMA(1, 1); POSTW(4);
  }
  #undef STAGE
  #undef DS_A
  #undef DS_B
  #undef PRE_MFMA
  #undef MMA
  #undef POSTW
  #undef POSTN

  #pragma unroll
  for (int qm = 0; qm < 2; ++qm)
    #pragma unroll
    for (int mm = 0; mm < 4; ++mm)
      #pragma unroll
      for (int qn = 0; qn < 2; ++qn)
        #pragma unroll
        for (int nn = 0; nn < 2; ++nn)
          #pragma unroll
          for (int ii = 0; ii < 4; ++ii) {
            const int rr = row0 + qm*128 + wr*64 + mm*16 + lq*4 + ii;
            const int cc = col0 + qn*128 + wc*32 + nn*16 + l15;
            const size_t idx = (size_t)rr * N + cc;
            const float v = acc[qm*4+mm][qn*2+nn][ii];
            if constexpr (EPI == 0) {
              outH[idx] = f2bf(v);
            } else if constexpr (EPI == 1) {
              outF[idx] = v + resid[idx];
            } else if constexpr (EPI == 2) {
              outH[idx] = f2bf(gelu_f(v + bias[cc]));
            } else {
              outF[idx] = v + bias[cc] + resid[idx];
            }
          }
}

// ---------------- scan prep: per (bh, chunk): cumsum gates, write qt/kt bf16, eac f32 ----------------
__global__ __launch_bounds__(128) void k_scanprep(const unsigned short* __restrict__ proj, const float* __restrict__ bgk,
                                                  unsigned short* __restrict__ qt, unsigned short* __restrict__ kt,
                                                  float* __restrict__ eac)
{
  const int c = blockIdx.x & 31, bh = blockIdx.x >> 5;
  const int b = bh >> 2, h = bh & 3;
  const int dk = threadIdx.x;
  const size_t tok0 = (size_t)b*2048 + c*64;
  const float bg = bgk[h*128 + dk];
  float A = 0.f, ea = 1.f;
  for (int t = 0; t < 64; ++t) {
    const size_t prow = (tok0 + t) * 3584;
    const float qv = bf2f(proj[prow + h*128 + dk]);
    const float kv = bf2f(proj[prow + 512 + h*128 + dk]);
    const float z = bf2f(proj[prow + 3072 + h*128 + dk]) + bg;
    const float az = fabsf(z);
    const float sp = fmaxf(-z, 0.f)
                   + 0.69314718f*__builtin_amdgcn_logf(1.f + __builtin_amdgcn_exp2f(-1.44269504f*az));
    A -= sp * 0.0625f;
    ea = __builtin_amdgcn_exp2f(A * 1.44269504f);
    const float em = __builtin_amdgcn_rcpf(ea);
    const size_t orow = ((size_t)bh*2048 + c*64 + t)*128 + dk;
    qt[orow] = f2bf(qv * ea * 0.08838834764831845f);
    kt[orow] = f2bf(kv * em);
  }
  eac[((size_t)bh*32 + c)*128 + dk] = ea;
}

// ---------------- MFMA chunk-state recurrence; stores S^T[dv][dk] at chunk START ----------------
__global__ __launch_bounds__(512) void k_seqstate(const unsigned short* __restrict__ ktt,
                                                  const unsigned short* __restrict__ vtg,
                                                  const float* __restrict__ eac,
                                                  unsigned short* __restrict__ sst)
{
  __shared__ __align__(16) unsigned short SLq[16384];
  const int bid = blockIdx.x;
  const int bh = bid >> 3, dks = (bid >> 2) & 1, dvs = bid & 3;
  const int tid = threadIdx.x, lane = tid & 63, w = tid >> 6;
  const int wr = w >> 2, wc = w & 3;
  const int l15 = lane & 15, lq = lane >> 4;
  const int kc8 = (lane & 7) * 8;

  #define SSTAGE(C, BUF)                                                        \
    { { const int o = w*512 + lane*8;                                           \
        const int dkl = o >> 6;                                                 \
        gload_lds16(&ktt[((size_t)bh*128 + dks*64 + dkl)*2048 + (C)*64 + (kc8 ^ ((dkl & 7) << 3))], \
                    (unsigned short*)&SLq[(BUF)*8192 + w*512]); }                \
      { const int o = w*512 + lane*8;                                           \
        const int dvl = o >> 6;                                                 \
        gload_lds16(&vtg[((size_t)bh*256 + dvs*64 + dvl)*2048 + (C)*64 + (kc8 ^ ((dvl & 7) << 3))], \
                    (unsigned short*)&SLq[(BUF)*8192 + 4096 + w*512]); } }

  f32x4 acc[2];
  acc[0][0]=0.f; acc[0][1]=0.f; acc[0][2]=0.f; acc[0][3]=0.f;
  acc[1] = acc[0];

  SSTAGE(0, 0);
  asm volatile("s_waitcnt vmcnt(0)" ::: "memory");
  __builtin_amdgcn_sched_barrier(0);
  __builtin_amdgcn_s_barrier();

  for (int c = 0; c < 32; ++c) {
    const int buf = c & 1;
    if (c + 1 < 32) {
      SSTAGE(c + 1, buf ^ 1);
      asm volatile("s_waitcnt vmcnt(2)" ::: "memory");
    } else {
      asm volatile("s_waitcnt vmcnt(0)" ::: "memory");
    }
    __builtin_amdgcn_sched_barrier(0);
    __builtin_amdgcn_s_barrier();

    const size_t srow = (((size_t)bh*32 + c)*256 + dvs*64 + wc*16 + l15)*128;
    #pragma unroll
    for (int mm = 0; mm < 2; ++mm) {
      u16x4 tj;
      tj[0]=f2bf(acc[mm][0]); tj[1]=f2bf(acc[mm][1]); tj[2]=f2bf(acc[mm][2]); tj[3]=f2bf(acc[mm][3]);
      *(u16x4*)&sst[srow + dks*64 + wr*32 + mm*16 + lq*4] = tj;
    }
    f32x4 ev[2];
    #pragma unroll
    for (int mm = 0; mm < 2; ++mm)
      ev[mm] = *(const f32x4*)&eac[(size_t)(bh*32 + c)*128 + dks*64 + wr*32 + mm*16 + lq*4];

    const int base = buf*8192;
    bf16x8 afr[2][2], bfrg[2];
    #pragma unroll
    for (int mm = 0; mm < 2; ++mm) {
      const int rl = wr*32 + mm*16 + l15;
      const int co = (rl & 7) << 3;
      afr[mm][0] = *(const bf16x8*)&SLq[base + rl*64 + ((lq*8) ^ co)];
      afr[mm][1] = *(const bf16x8*)&SLq[base + rl*64 + ((32 + lq*8) ^ co)];
    }
    {
      const int dvl = wc*16 + l15;
      const int co = (dvl & 7) << 3;
      bfrg[0] = *(const bf16x8*)&SLq[base + 4096 + dvl*64 + ((lq*8) ^ co)];
      bfrg[1] = *(const bf16x8*)&SLq[base + 4096 + dvl*64 + ((32 + lq*8) ^ co)];
    }
    asm volatile("s_waitcnt lgkmcnt(0)" ::: "memory");
    __builtin_amdgcn_sched_barrier(0);
    #pragma unroll
    for (int k4 = 0; k4 < 2; ++k4)
      #pragma unroll
      for (int mm = 0; mm < 2; ++mm)
        acc[mm] = __builtin_amdgcn_mfma_f32_16x16x32_bf16(afr[mm][k4], bfrg[k4], acc[mm], 0, 0, 0);
    #pragma unroll
    for (int mm = 0; mm < 2; ++mm)
      #pragma unroll
      for (int i = 0; i < 4; ++i)
        acc[mm][i] *= ev[mm][i];
    __builtin_amdgcn_s_barrier();
  }
  #undef SSTAGE
}

// ---------------- fused MFMA attn out: P=tril(QK^T); O=P@V+Q@S0; rmsnorm*g*sig(g) -> og ----------------
__global__ __launch_bounds__(512) void k_attn_out(const unsigned short* __restrict__ qt,
                                                  const unsigned short* __restrict__ kt,
                                                  const unsigned short* __restrict__ vtg,
                                                  const unsigned short* __restrict__ sst,
                                                  const unsigned short* __restrict__ proj,
                                                  const float* __restrict__ gnw,
                                                  unsigned short* __restrict__ og)
{
  __shared__ __align__(16) unsigned short SL[61440];
  __shared__ float ssq[64];
  const int c = blockIdx.x & 31, bh = blockIdx.x >> 5;
  const int b = bh >> 2, h = bh & 3;
  const int tid = threadIdx.x, lane = tid & 63, w = tid >> 6;
  const int wr = w >> 2, wc = w & 3;
  const int l15 = lane & 15, lq = lane >> 4;
  const size_t qk0 = (size_t)bh*2048 + c*64;
  const size_t tok0 = (size_t)b*2048 + c*64;
  const int key15 = (l15 & 7) << 3;

  if (tid < 64) ssq[tid] = 0.f;

  const int kc8 = (lane & 7) * 8;
  #pragma unroll
  for (int it = 0; it < 2; ++it) {
    const int o = it*4096 + w*512 + lane*8;
    const int ch = o >> 12, r = (o >> 6) & 63;
    gload_lds16(&kt[(qk0 + r)*128 + ch*64 + (kc8 ^ ((r & 7) << 3))],
                (unsigned short*)&SL[53248 + it*4096 + w*512]);
  }
  #pragma unroll
  for (int it = 0; it < 4; ++it) {
    const int o = it*4096 + w*512 + lane*8;
    const int dv = o >> 6;
    gload_lds16(&vtg[((size_t)bh*256 + dv)*2048 + c*64 + (kc8 ^ ((dv & 7) << 3))],
                (unsigned short*)&SL[4096 + it*4096 + w*512]);
  }
  #pragma unroll
  for (int it = 0; it < 8; ++it) {
    const int o = it*4096 + w*512 + lane*8;
    const int ch = o >> 14, dv = (o >> 6) & 255;
    gload_lds16(&sst[((size_t)(bh*32 + c)*256 + dv)*128 + ch*64 + (kc8 ^ ((dv & 7) << 3))],
                (unsigned short*)&SL[20480 + it*4096 + w*512]);
  }
  bf16x8 aq[2][4];
  #pragma unroll
  for (int mm = 0; mm < 2; ++mm)
    #pragma unroll
    for (int k4 = 0; k4 < 4; ++k4)
      aq[mm][k4] = *(const bf16x8*)&qt[(qk0 + wr*32 + mm*16 + l15)*128 + k4*32 + lq*8];

  __syncthreads();

  f32x4 accp[2];
  accp[0][0]=0.f; accp[0][1]=0.f; accp[0][2]=0.f; accp[0][3]=0.f;
  accp[1] = accp[0];
  #pragma unroll
  for (int k4 = 0; k4 < 4; ++k4) {
    const int ch = k4 >> 1, k0c = (k4 & 1) * 32;
    const bf16x8 bk = *(const bf16x8*)&SL[53248 + ch*4096 + (wc*16 + l15)*64 + ((k0c + lq*8) ^ key15)];
    accp[0] = __builtin_amdgcn_mfma_f32_16x16x32_bf16(aq[0][k4], bk, accp[0], 0, 0, 0);
    accp[1] = __builtin_amdgcn_mfma_f32_16x16x32_bf16(aq[1][k4], bk, accp[1], 0, 0, 0);
  }
  #pragma unroll
  for (int mm = 0; mm < 2; ++mm)
    #pragma unroll
    for (int i = 0; i < 4; ++i) {
      const int rg = wr*32 + mm*16 + lq*4 + i;
      const int cg = wc*16 + l15;
      SL[rg*64 + (cg ^ ((rg & 7) << 3))] = f2bf((cg <= rg) ? accp[mm][i] : 0.f);
    }
  __syncthreads();

  f32x4 acco[2][4];
  #pragma unroll
  for (int mm = 0; mm < 2; ++mm)
    #pragma unroll
    for (int nn = 0; nn < 4; ++nn) { acco[mm][nn][0]=0.f; acco[mm][nn][1]=0.f; acco[mm][nn][2]=0.f; acco[mm][nn][3]=0.f; }

  #pragma unroll
  for (int t4 = 0; t4 < 2; ++t4) {
    bf16x8 ap[2];
    #pragma unroll
    for (int mm = 0; mm < 2; ++mm) {
      const int r = wr*32 + mm*16 + l15;
      ap[mm] = *(const bf16x8*)&SL[r*64 + ((t4*32 + lq*8) ^ key15)];
    }
    #pragma unroll
    for (int nn = 0; nn < 4; ++nn) {
      const int dv = wc*64 + nn*16 + l15;
      const bf16x8 bv = *(const bf16x8*)&SL[4096 + dv*64 + ((t4*32 + lq*8) ^ key15)];
      acco[0][nn] = __builtin_amdgcn_mfma_f32_16x16x32_bf16(ap[0], bv, acco[0][nn], 0, 0, 0);
      acco[1][nn] = __builtin_amdgcn_mfma_f32_16x16x32_bf16(ap[1], bv, acco[1][nn], 0, 0, 0);
    }
  }
  #pragma unroll
  for (int k4 = 0; k4 < 4; ++k4) {
    const int ch = k4 >> 1, k0c = (k4 & 1) * 32;
    #pragma unroll
    for (int nn = 0; nn < 4; ++nn) {
      const int dv = wc*64 + nn*16 + l15;
      const bf16x8 bs = *(const bf16x8*)&SL[20480 + ch*16384 + dv*64 + ((k0c + lq*8) ^ key15)];
      acco[0][nn] = __builtin_amdgcn_mfma_f32_16x16x32_bf16(aq[0][k4], bs, acco[0][nn], 0, 0, 0);
      acco[1][nn] = __builtin_amdgcn_mfma_f32_16x16x32_bf16(aq[1][k4], bs, acco[1][nn], 0, 0, 0);
    }
  }

  #pragma unroll
  for (int mm = 0; mm < 2; ++mm) {
    float part[4];
    #pragma unroll
    for (int i = 0; i < 4; ++i) {
      float s = 0.f;
      #pragma unroll
      for (int nn = 0; nn < 4; ++nn) s += acco[mm][nn][i]*acco[mm][nn][i];
      s += __shfl_xor(s, 1); s += __shfl_xor(s, 2); s += __shfl_xor(s, 4); s += __shfl_xor(s, 8);
      part[i] = s;
    }
    if (l15 == 0) {
      #pragma unroll
      for (int i = 0; i < 4; ++i)
        atomicAdd(&ssq[wr*32 + mm*16 + lq*4 + i], part[i]);
    }
  }
  __syncthreads();

  #pragma unroll
  for (int mm = 0; mm < 2; ++mm)
    #pragma unroll
    for (int i = 0; i < 4; ++i) {
      const int rg = wr*32 + mm*16 + lq*4 + i;
      const float rs = rsqrtf(ssq[rg] * (1.f/256.f) + 1e-5f);
      const size_t token = tok0 + rg;
      #pragma unroll
      for (int nn = 0; nn < 4; ++nn) {
        const int dv = wc*64 + nn*16 + l15;
        const float gf = bf2f(proj[token*3584 + 2048 + h*256 + dv]);
        const float swv = gf * __builtin_amdgcn_rcpf(1.f + __builtin_amdgcn_exp2f(-1.44269504f*gf));
        og[token*1024 + h*256 + dv] = f2bf(acco[mm][nn][i] * rs * gnw[dv] * swv);
      }
    }
}

extern "C" void kernel_launch(void* const* d_in, const int* in_sizes, int n_in,
                              void* d_out, int out_size, void* d_ws, size_t ws_size,
                              hipStream_t stream)
{
  (void)in_sizes; (void)n_in; (void)out_size; (void)ws_size;
  const float* x    = (const float*)d_in[0];
  const float* ln1g = (const float*)d_in[1];
  const float* ln1b = (const float*)d_in[2];
  const float* Wq   = (const float*)d_in[3];
  const float* Wk   = (const float*)d_in[4];
  const float* Wv   = (const float*)d_in[5];
  const float* Wg   = (const float*)d_in[6];
  const float* Wgk1 = (const float*)d_in[7];
  const float* Wgk2 = (const float*)d_in[8];
  const float* bgk  = (const float*)d_in[9];
  const float* gnw  = (const float*)d_in[10];
  const float* Wo   = (const float*)d_in[11];
  const float* ln2g = (const float*)d_in[12];
  const float* ln2b = (const float*)d_in[13];
  const float* W1   = (const float*)d_in[14];
  const float* b1   = (const float*)d_in[15];
  const float* W2   = (const float*)d_in[16];
  const float* b2   = (const float*)d_in[17];
  float* out = (float*)d_out;
  char* ws = (char*)d_ws;

  u16t*  XN   = (u16t*)(ws + 0);
  u16t*  KTT  = (u16t*)(ws + 0);
  u16t*  OG   = (u16t*)(ws + 0);
  u16t*  WPT  = (u16t*)(ws + 33554432);
  u16t*  WOT  = (u16t*)(ws + 40894464);
  u16t*  W1T  = (u16t*)(ws + 42991616);
  u16t*  W2T  = (u16t*)(ws + 51380224);
  u16t*  PROJ = (u16t*)(ws + 59768832);
  u16t*  QT   = (u16t*)(ws + 177209344);
  u16t*  KT   = (u16t*)(ws + 193986560);
  float* EAC  = (float*)(ws + 210763776);
  u16t*  VT   = (u16t*)(ws + 211288064);
  u16t*  H2   = (u16t*)(ws + 211288064);
  u16t*  HID  = PROJ;
  u16t*  SST  = (u16t*)d_out;

  k_transpose_multi<<<12288, dim3(32,8), 0, stream>>>(Wq, Wk, Wv, Wg, Wo, W1, W2, WPT, WOT, W1T, W2T);
  k_wgk<<<2048, 256, 0, stream>>>(Wgk1, Wgk2, WPT + (size_t)3072*1024);

  k_layernorm<<<16384, 256, 0, stream>>>(x, ln1g, ln1b, XN);
  gemm256<0><<<dim3(14,64), 512, 0, stream>>>(XN, WPT, 3584, 1024, nullptr, PROJ, nullptr, nullptr);
  k_scanprep<<<1024, 128, 0, stream>>>(PROJ, bgk, QT, KT, EAC);
  k_vtrans<<<dim3(64,12,32), dim3(32,8), 0, stream>>>(PROJ, KT, VT, KTT);
  k_seqstate<<<256, 512, 0, stream>>>(KTT, VT, EAC, SST);
  k_attn_out<<<1024, 512, 0, stream>>>(QT, KT, VT, SST, PROJ, gnw, OG);
  gemm256<1><<<dim3(4,64),  512, 0, stream>>>(OG, WOT, 1024, 1024, out, nullptr, x, nullptr);   // x1 = o@Wo + x
  k_layernorm<<<16384, 256, 0, stream>>>(out, ln2g, ln2b, H2);
  gemm256<2><<<dim3(16,64), 512, 0, stream>>>(H2, W1T, 4096, 1024, nullptr, HID, nullptr, b1);  // gelu(h@W1+b1)
  gemm256<3><<<dim3(4,64),  512, 0, stream>>>(HID, W2T, 1024, 4096, out, nullptr, out, b2);     // out = x1 + hid@W2 + b2
}

// Round 11
// 672.369 us; speedup vs baseline: 1.0312x; 1.0312x over previous
//
#include <hip/hip_runtime.h>
#include <stdint.h>

// GLA block for MI355X (gfx950).
// B=8 S=2048 D=1024 H=4 DK=128 DV=256 CHUNK=64 (32 chunks), MLP_H=4096.
// R11: gemm256 -> 16 waves (1024 thr), wave tile 64x64 (acc 64 regs), frags
// loaded per K-half (live ~112 regs) => 3-4 waves/SIMD instead of 2. Simple
// dbuf loop (vmcnt(4), 2 barriers + 1 mid lgkm split per tile). Occupancy was
// the binding constraint (R10: 22% occ, 3 schedules all ~34% MfmaUtil).

typedef unsigned short u16t;
typedef __attribute__((ext_vector_type(8))) short bf16x8;
typedef __attribute__((ext_vector_type(4))) float f32x4;
typedef __attribute__((ext_vector_type(4))) unsigned short u16x4;

__device__ __forceinline__ float bf2f(unsigned short u){ union{unsigned int i; float f;} v; v.i=((unsigned int)u)<<16; return v.f; }
__device__ __forceinline__ unsigned short f2bf(float f){ union{unsigned int i; float f;} v; v.f=f; unsigned int r=v.i+0x7FFFu+((v.i>>16)&1u); return (unsigned short)(r>>16); }
__device__ __forceinline__ f32x4 cvt4(u16x4 u){ f32x4 r; r[0]=bf2f(u[0]); r[1]=bf2f(u[1]); r[2]=bf2f(u[2]); r[3]=bf2f(u[3]); return r; }

// fast tanh-GELU (native exp2/rcp); |err| vs exact-erf gelu ~3e-4.
__device__ __forceinline__ float gelu_f(float t){
  const float t3 = t*t*t;
  const float y = 2.3021183f*t + 0.10295465f*t3;
  const float e = __builtin_amdgcn_exp2f(y);
  return t - t*__builtin_amdgcn_rcpf(e + 1.f);
}

__device__ __forceinline__ void gload_lds16(const unsigned short* g, unsigned short* l)
{
  __builtin_amdgcn_global_load_lds(
      (const __attribute__((address_space(1))) unsigned int*)g,
      (__attribute__((address_space(3))) unsigned int*)l,
      16, 0, 0);
}

// ---------------- merged transpose f32 [Kin][N] -> bf16 [N][Kin], 7 weights ----------------
__global__ void k_transpose_multi(const float* __restrict__ Wq, const float* __restrict__ Wk,
                                  const float* __restrict__ Wv, const float* __restrict__ Wg,
                                  const float* __restrict__ Wo, const float* __restrict__ W1,
                                  const float* __restrict__ W2,
                                  unsigned short* __restrict__ WPT, unsigned short* __restrict__ WOT,
                                  unsigned short* __restrict__ W1T, unsigned short* __restrict__ W2T)
{
  __shared__ float tile[32][33];
  int bid = blockIdx.x;
  const float* src; unsigned short* dst; int Kin, N, nx;
  if      (bid < 512)  { src=Wq; dst=WPT;                          Kin=1024; N=512;  nx=16;  }
  else if (bid < 1024) { src=Wk; dst=WPT+(size_t)512*1024;         Kin=1024; N=512;  nx=16;  bid-=512;  }
  else if (bid < 2048) { src=Wv; dst=WPT+(size_t)1024*1024;        Kin=1024; N=1024; nx=32;  bid-=1024; }
  else if (bid < 3072) { src=Wg; dst=WPT+(size_t)2048*1024;        Kin=1024; N=1024; nx=32;  bid-=2048; }
  else if (bid < 4096) { src=Wo; dst=WOT;                          Kin=1024; N=1024; nx=32;  bid-=3072; }
  else if (bid < 8192) { src=W1; dst=W1T;                          Kin=1024; N=4096; nx=128; bid-=4096; }
  else                 { src=W2; dst=W2T;                          Kin=4096; N=1024; nx=32;  bid-=8192; }
  const int n0 = (bid % nx)*32, k0 = (bid / nx)*32;
  const int tx = threadIdx.x, ty = threadIdx.y;
  #pragma unroll
  for (int i = 0; i < 4; ++i)
    tile[ty + i*8][tx] = src[(size_t)(k0 + ty + i*8)*N + n0 + tx];
  __syncthreads();
  #pragma unroll
  for (int i = 0; i < 4; ++i)
    dst[(size_t)(n0 + ty + i*8)*Kin + k0 + tx] = f2bf(tile[tx][ty + i*8]);
}

// ---------------- Wgk = Wgk1[1024,16] @ Wgk2[16,512] -> bf16 transposed rows [512][1024] ----------------
__global__ void k_wgk(const float* __restrict__ Wgk1, const float* __restrict__ Wgk2, unsigned short* __restrict__ dstT)
{
  const int idx = blockIdx.x*256 + threadIdx.x;
  const int i = idx & 1023, j = idx >> 10;
  float s = 0.f;
  #pragma unroll
  for (int r = 0; r < 16; ++r) s += Wgk1[i*16 + r] * Wgk2[r*512 + j];
  dstT[(size_t)j*1024 + i] = f2bf(s);
}

// ---------------- V/K transpose: proj v-cols -> VT[bh][256][2048]; kt -> KTT[bh][128][2048] ----------------
__global__ void k_vtrans(const unsigned short* __restrict__ proj, const unsigned short* __restrict__ kt,
                         unsigned short* __restrict__ vtg, unsigned short* __restrict__ ktt)
{
  __shared__ unsigned short tile[32][33];
  const int tt = blockIdx.x, zz = blockIdx.y, bh = blockIdx.z;
  const int b = bh >> 2, h = bh & 3;
  const int tx = threadIdx.x, ty = threadIdx.y;
  if (zz < 8) {
    const int dvt = zz;
    #pragma unroll
    for (int i = 0; i < 4; ++i)
      tile[ty + i*8][tx] = proj[((size_t)b*2048 + tt*32 + ty + i*8)*3584 + 1024 + h*256 + dvt*32 + tx];
    __syncthreads();
    #pragma unroll
    for (int i = 0; i < 4; ++i)
      vtg[((size_t)bh*256 + dvt*32 + ty + i*8)*2048 + tt*32 + tx] = tile[tx][ty + i*8];
  } else {
    const int dkt = zz - 8;
    #pragma unroll
    for (int i = 0; i < 4; ++i)
      tile[ty + i*8][tx] = kt[((size_t)bh*2048 + tt*32 + ty + i*8)*128 + dkt*32 + tx];
    __syncthreads();
    #pragma unroll
    for (int i = 0; i < 4; ++i)
      ktt[((size_t)bh*128 + dkt*32 + ty + i*8)*2048 + tt*32 + tx] = tile[tx][ty + i*8];
  }
}

// ---------------- LayerNorm row=1024, f32 in -> bf16 out ----------------
__global__ __launch_bounds__(256) void k_layernorm(const float* __restrict__ x, const float* __restrict__ g,
                                                   const float* __restrict__ b, unsigned short* __restrict__ out)
{
  const int row = blockIdx.x, tid = threadIdx.x;
  const float4 xv = *(const float4*)&x[(size_t)row*1024 + tid*4];
  float s  = xv.x + xv.y + xv.z + xv.w;
  float sq = xv.x*xv.x + xv.y*xv.y + xv.z*xv.z + xv.w*xv.w;
  #pragma unroll
  for (int o = 32; o > 0; o >>= 1) { s += __shfl_xor(s, o); sq += __shfl_xor(sq, o); }
  __shared__ float red[8];
  const int w = tid >> 6;
  if ((tid & 63) == 0) { red[w] = s; red[4 + w] = sq; }
  __syncthreads();
  s  = red[0] + red[1] + red[2] + red[3];
  sq = red[4] + red[5] + red[6] + red[7];
  const float mu = s * (1.f/1024.f);
  const float var = sq * (1.f/1024.f) - mu*mu;
  const float rs = rsqrtf(var + 1e-5f);
  float xe[4] = {xv.x, xv.y, xv.z, xv.w};
  u16x4 o4;
  #pragma unroll
  for (int i = 0; i < 4; ++i) {
    const int c = tid*4 + i;
    o4[i] = f2bf((xe[i] - mu) * rs * g[c] + b[c]);
  }
  *(u16x4*)&out[(size_t)row*1024 + tid*4] = o4;
}

// ---------------- 256x256 16-wave bf16 MFMA GEMM: C = A[M,K] @ Bt[N,K]^T ----------------
// 1024 threads = 16 waves (4wr x 4wc); per-wave 64x64 output (4x4 frags).
// LDS: 2 bufs x 4 chunks {Ah0,Ah1,Bh0,Bh1} x 16KB = 128 KiB, XOR-swizzled.
// Loop: STAGE(t+1) 4 gloads; vmcnt(4); barrier; per K-half {8 ds_read; lgkm0;
// 16 MFMA}; WAR barrier after half-1 reads. acc = 64 regs -> 3-4 waves/SIMD.
// EPI: 0 = store bf16; 1 = +resid -> f32; 2 = +bias, gelu -> bf16; 3 = +bias +resid -> f32
template<int EPI>
__global__ __launch_bounds__(1024, 3)
void gemm256(const unsigned short* __restrict__ A, const unsigned short* __restrict__ Bt,
             int N, int K,
             float* outF, unsigned short* outH,
             const float* resid, const float* bias)
{
  __shared__ __align__(16) unsigned short lds[65536];   // 128 KiB
  const int tid = threadIdx.x;
  const int lane = tid & 63, w = tid >> 6;
  const int wr = w >> 2, wc = w & 3;
  const int l15 = lane & 15, lq = lane >> 4;

  // bijective XCD-aware swizzle (m204)
  const int nwg = gridDim.x * gridDim.y;
  const int bid = blockIdx.y * gridDim.x + blockIdx.x;
  const int q = nwg >> 3, r = nwg & 7;
  const int xcd = bid & 7, lid = bid >> 3;
  const int sw = (xcd < r ? xcd*(q+1) : r*(q+1) + (xcd - r)*q) + lid;
  const int row0 = (sw / gridDim.x) * 256;
  const int col0 = (sw % gridDim.x) * 256;

  // staging: 1024 thr x 16B = one 16KB chunk (128 rows x 64 cols) per issue.
  const int rA_ = tid >> 3;                              // 0..127 row within chunk
  const int cswz = 8 * ((tid & 7) ^ (rA_ & 7));          // pre-swizzled source col
  const unsigned short* baseA[2];
  const unsigned short* baseB[2];
  #pragma unroll
  for (int h = 0; h < 2; ++h) {
    baseA[h] = A  + (size_t)(row0 + h*128 + rA_) * K + cswz;
    baseB[h] = Bt + (size_t)(col0 + h*128 + rA_) * K + cswz;
  }

  const int NT = K >> 6;

  f32x4 acc[4][4];
  #pragma unroll
  for (int m = 0; m < 4; ++m)
    #pragma unroll
    for (int n = 0; n < 4; ++n) { acc[m][n][0]=0.f; acc[m][n][1]=0.f; acc[m][n][2]=0.f; acc[m][n][3]=0.f; }

  // wave's chunk bases (within a buffer): A chunk = (wr>>1), B chunk = 2+(wc>>1)
  const int carA = (wr >> 1) * 8192;
  const int carB = 16384 + (wc >> 1) * 8192;
  const int rowA = (wr & 1) * 64;     // row offset within 128-row chunk
  const int rowB = (wc & 1) * 64;
  const int co = (l15 & 7) * 8;       // read-side XOR key

  #define STAGE4(T)                                                            \
    {                                                                          \
      const int dbase = ((T) & 1) * 32768;                                     \
      const int ktt2 = (T) << 6;                                               \
      gload_lds16(baseA[0] + ktt2, (unsigned short*)&lds[dbase +         w*512]); \
      gload_lds16(baseA[1] + ktt2, (unsigned short*)&lds[dbase +  8192 + w*512]); \
      gload_lds16(baseB[0] + ktt2, (unsigned short*)&lds[dbase + 16384 + w*512]); \
      gload_lds16(baseB[1] + ktt2, (unsigned short*)&lds[dbase + 24576 + w*512]); \
    }

  #define MMAH(BUF, H)                                                         \
    {                                                                          \
      bf16x8 af[4], bfr[4];                                                    \
      _Pragma("unroll")                                                        \
      for (int mm = 0; mm < 4; ++mm)                                           \
        af[mm] = *(const bf16x8*)&lds[(BUF) + carA + (rowA + mm*16 + l15)*64   \
                                      + (((H)*32 + lq*8) ^ co)];               \
      _Pragma("unroll")                                                        \
      for (int nn = 0; nn < 4; ++nn)                                           \
        bfr[nn] = *(const bf16x8*)&lds[(BUF) + carB + (rowB + nn*16 + l15)*64  \
                                       + (((H)*32 + lq*8) ^ co)];              \
      asm volatile("s_waitcnt lgkmcnt(0)" ::: "memory");                       \
      __builtin_amdgcn_sched_barrier(0);                                       \
      if (H) { __builtin_amdgcn_s_barrier(); }  /* WAR: all reads of buf done */ \
      __builtin_amdgcn_s_setprio(1);                                           \
      _Pragma("unroll")                                                        \
      for (int mm = 0; mm < 4; ++mm)                                           \
        _Pragma("unroll")                                                      \
        for (int nn = 0; nn < 4; ++nn)                                         \
          acc[mm][nn] = __builtin_amdgcn_mfma_f32_16x16x32_bf16(               \
              af[mm], bfr[nn], acc[mm][nn], 0, 0, 0);                          \
      __builtin_amdgcn_s_setprio(0);                                           \
    }

  STAGE4(0);
  for (int t = 0; t < NT; ++t) {
    const int buf = (t & 1) * 32768;
    if (t + 1 < NT) {
      STAGE4(t + 1);
      asm volatile("s_waitcnt vmcnt(4)" ::: "memory");   // tile t's 4 loads landed
    } else {
      asm volatile("s_waitcnt vmcnt(0)" ::: "memory");
    }
    __builtin_amdgcn_sched_barrier(0);
    __builtin_amdgcn_s_barrier();          // tile t ready for all waves
    MMAH(buf, 0);
    MMAH(buf, 1);                          // includes WAR barrier before MFMA
  }
  #undef STAGE4
  #undef MMAH

  // epilogue
  #pragma unroll
  for (int mm = 0; mm < 4; ++mm)
    #pragma unroll
    for (int nn = 0; nn < 4; ++nn)
      #pragma unroll
      for (int ii = 0; ii < 4; ++ii) {
        const int rr = row0 + wr*64 + mm*16 + lq*4 + ii;
        const int cc = col0 + wc*64 + nn*16 + l15;
        const size_t idx = (size_t)rr * N + cc;
        const float v = acc[mm][nn][ii];
        if constexpr (EPI == 0) {
          outH[idx] = f2bf(v);
        } else if constexpr (EPI == 1) {
          outF[idx] = v + resid[idx];
        } else if constexpr (EPI == 2) {
          outH[idx] = f2bf(gelu_f(v + bias[cc]));
        } else {
          outF[idx] = v + bias[cc] + resid[idx];
        }
      }
}

// ---------------- scan prep: per (bh, chunk): cumsum gates, write qt/kt bf16, eac f32 ----------------
__global__ __launch_bounds__(128) void k_scanprep(const unsigned short* __restrict__ proj, const float* __restrict__ bgk,
                                                  unsigned short* __restrict__ qt, unsigned short* __restrict__ kt,
                                                  float* __restrict__ eac)
{
  const int c = blockIdx.x & 31, bh = blockIdx.x >> 5;
  const int b = bh >> 2, h = bh & 3;
  const int dk = threadIdx.x;
  const size_t tok0 = (size_t)b*2048 + c*64;
  const float bg = bgk[h*128 + dk];
  float A = 0.f, ea = 1.f;
  for (int t = 0; t < 64; ++t) {
    const size_t prow = (tok0 + t) * 3584;
    const float qv = bf2f(proj[prow + h*128 + dk]);
    const float kv = bf2f(proj[prow + 512 + h*128 + dk]);
    const float z = bf2f(proj[prow + 3072 + h*128 + dk]) + bg;
    const float az = fabsf(z);
    const float sp = fmaxf(-z, 0.f)
                   + 0.69314718f*__builtin_amdgcn_logf(1.f + __builtin_amdgcn_exp2f(-1.44269504f*az));
    A -= sp * 0.0625f;
    ea = __builtin_amdgcn_exp2f(A * 1.44269504f);
    const float em = __builtin_amdgcn_rcpf(ea);
    const size_t orow = ((size_t)bh*2048 + c*64 + t)*128 + dk;
    qt[orow] = f2bf(qv * ea * 0.08838834764831845f);
    kt[orow] = f2bf(kv * em);
  }
  eac[((size_t)bh*32 + c)*128 + dk] = ea;
}

// ---------------- MFMA chunk-state recurrence; stores S^T[dv][dk] at chunk START ----------------
__global__ __launch_bounds__(512) void k_seqstate(const unsigned short* __restrict__ ktt,
                                                  const unsigned short* __restrict__ vtg,
                                                  const float* __restrict__ eac,
                                                  unsigned short* __restrict__ sst)
{
  __shared__ __align__(16) unsigned short SLq[16384];
  const int bid = blockIdx.x;
  const int bh = bid >> 3, dks = (bid >> 2) & 1, dvs = bid & 3;
  const int tid = threadIdx.x, lane = tid & 63, w = tid >> 6;
  const int wr = w >> 2, wc = w & 3;
  const int l15 = lane & 15, lq = lane >> 4;
  const int kc8 = (lane & 7) * 8;

  #define SSTAGE(C, BUF)                                                        \
    { { const int o = w*512 + lane*8;                                           \
        const int dkl = o >> 6;                                                 \
        gload_lds16(&ktt[((size_t)bh*128 + dks*64 + dkl)*2048 + (C)*64 + (kc8 ^ ((dkl & 7) << 3))], \
                    (unsigned short*)&SLq[(BUF)*8192 + w*512]); }                \
      { const int o = w*512 + lane*8;                                           \
        const int dvl = o >> 6;                                                 \
        gload_lds16(&vtg[((size_t)bh*256 + dvs*64 + dvl)*2048 + (C)*64 + (kc8 ^ ((dvl & 7) << 3))], \
                    (unsigned short*)&SLq[(BUF)*8192 + 4096 + w*512]); } }

  f32x4 acc[2];
  acc[0][0]=0.f; acc[0][1]=0.f; acc[0][2]=0.f; acc[0][3]=0.f;
  acc[1] = acc[0];

  SSTAGE(0, 0);
  asm volatile("s_waitcnt vmcnt(0)" ::: "memory");
  __builtin_amdgcn_sched_barrier(0);
  __builtin_amdgcn_s_barrier();

  for (int c = 0; c < 32; ++c) {
    const int buf = c & 1;
    if (c + 1 < 32) {
      SSTAGE(c + 1, buf ^ 1);
      asm volatile("s_waitcnt vmcnt(2)" ::: "memory");
    } else {
      asm volatile("s_waitcnt vmcnt(0)" ::: "memory");
    }
    __builtin_amdgcn_sched_barrier(0);
    __builtin_amdgcn_s_barrier();

    const size_t srow = (((size_t)bh*32 + c)*256 + dvs*64 + wc*16 + l15)*128;
    #pragma unroll
    for (int mm = 0; mm < 2; ++mm) {
      u16x4 tj;
      tj[0]=f2bf(acc[mm][0]); tj[1]=f2bf(acc[mm][1]); tj[2]=f2bf(acc[mm][2]); tj[3]=f2bf(acc[mm][3]);
      *(u16x4*)&sst[srow + dks*64 + wr*32 + mm*16 + lq*4] = tj;
    }
    f32x4 ev[2];
    #pragma unroll
    for (int mm = 0; mm < 2; ++mm)
      ev[mm] = *(const f32x4*)&eac[(size_t)(bh*32 + c)*128 + dks*64 + wr*32 + mm*16 + lq*4];

    const int base = buf*8192;
    bf16x8 afr[2][2], bfrg[2];
    #pragma unroll
    for (int mm = 0; mm < 2; ++mm) {
      const int rl = wr*32 + mm*16 + l15;
      const int co = (rl & 7) << 3;
      afr[mm][0] = *(const bf16x8*)&SLq[base + rl*64 + ((lq*8) ^ co)];
      afr[mm][1] = *(const bf16x8*)&SLq[base + rl*64 + ((32 + lq*8) ^ co)];
    }
    {
      const int dvl = wc*16 + l15;
      const int co = (dvl & 7) << 3;
      bfrg[0] = *(const bf16x8*)&SLq[base + 4096 + dvl*64 + ((lq*8) ^ co)];
      bfrg[1] = *(const bf16x8*)&SLq[base + 4096 + dvl*64 + ((32 + lq*8) ^ co)];
    }
    asm volatile("s_waitcnt lgkmcnt(0)" ::: "memory");
    __builtin_amdgcn_sched_barrier(0);
    #pragma unroll
    for (int k4 = 0; k4 < 2; ++k4)
      #pragma unroll
      for (int mm = 0; mm < 2; ++mm)
        acc[mm] = __builtin_amdgcn_mfma_f32_16x16x32_bf16(afr[mm][k4], bfrg[k4], acc[mm], 0, 0, 0);
    #pragma unroll
    for (int mm = 0; mm < 2; ++mm)
      #pragma unroll
      for (int i = 0; i < 4; ++i)
        acc[mm][i] *= ev[mm][i];
    __builtin_amdgcn_s_barrier();
  }
  #undef SSTAGE
}

// ---------------- fused MFMA attn out: P=tril(QK^T); O=P@V+Q@S0; rmsnorm*g*sig(g) -> og ----------------
__global__ __launch_bounds__(512) void k_attn_out(const unsigned short* __restrict__ qt,
                                                  const unsigned short* __restrict__ kt,
                                                  const unsigned short* __restrict__ vtg,
                                                  const unsigned short* __restrict__ sst,
                                                  const unsigned short* __restrict__ proj,
                                                  const float* __restrict__ gnw,
                                                  unsigned short* __restrict__ og)
{
  __shared__ __align__(16) unsigned short SL[61440];
  __shared__ float ssq[64];
  const int c = blockIdx.x & 31, bh = blockIdx.x >> 5;
  const int b = bh >> 2, h = bh & 3;
  const int tid = threadIdx.x, lane = tid & 63, w = tid >> 6;
  const int wr = w >> 2, wc = w & 3;
  const int l15 = lane & 15, lq = lane >> 4;
  const size_t qk0 = (size_t)bh*2048 + c*64;
  const size_t tok0 = (size_t)b*2048 + c*64;
  const int key15 = (l15 & 7) << 3;

  if (tid < 64) ssq[tid] = 0.f;

  const int kc8 = (lane & 7) * 8;
  #pragma unroll
  for (int it = 0; it < 2; ++it) {
    const int o = it*4096 + w*512 + lane*8;
    const int ch = o >> 12, r = (o >> 6) & 63;
    gload_lds16(&kt[(qk0 + r)*128 + ch*64 + (kc8 ^ ((r & 7) << 3))],
                (unsigned short*)&SL[53248 + it*4096 + w*512]);
  }
  #pragma unroll
  for (int it = 0; it < 4; ++it) {
    const int o = it*4096 + w*512 + lane*8;
    const int dv = o >> 6;
    gload_lds16(&vtg[((size_t)bh*256 + dv)*2048 + c*64 + (kc8 ^ ((dv & 7) << 3))],
                (unsigned short*)&SL[4096 + it*4096 + w*512]);
  }
  #pragma unroll
  for (int it = 0; it < 8; ++it) {
    const int o = it*4096 + w*512 + lane*8;
    const int ch = o >> 14, dv = (o >> 6) & 255;
    gload_lds16(&sst[((size_t)(bh*32 + c)*256 + dv)*128 + ch*64 + (kc8 ^ ((dv & 7) << 3))],
                (unsigned short*)&SL[20480 + it*4096 + w*512]);
  }
  bf16x8 aq[2][4];
  #pragma unroll
  for (int mm = 0; mm < 2; ++mm)
    #pragma unroll
    for (int k4 = 0; k4 < 4; ++k4)
      aq[mm][k4] = *(const bf16x8*)&qt[(qk0 + wr*32 + mm*16 + l15)*128 + k4*32 + lq*8];

  __syncthreads();

  f32x4 accp[2];
  accp[0][0]=0.f; accp[0][1]=0.f; accp[0][2]=0.f; accp[0][3]=0.f;
  accp[1] = accp[0];
  #pragma unroll
  for (int k4 = 0; k4 < 4; ++k4) {
    const int ch = k4 >> 1, k0c = (k4 & 1) * 32;
    const bf16x8 bk = *(const bf16x8*)&SL[53248 + ch*4096 + (wc*16 + l15)*64 + ((k0c + lq*8) ^ key15)];
    accp[0] = __builtin_amdgcn_mfma_f32_16x16x32_bf16(aq[0][k4], bk, accp[0], 0, 0, 0);
    accp[1] = __builtin_amdgcn_mfma_f32_16x16x32_bf16(aq[1][k4], bk, accp[1], 0, 0, 0);
  }
  #pragma unroll
  for (int mm = 0; mm < 2; ++mm)
    #pragma unroll
    for (int i = 0; i < 4; ++i) {
      const int rg = wr*32 + mm*16 + lq*4 + i;
      const int cg = wc*16 + l15;
      SL[rg*64 + (cg ^ ((rg & 7) << 3))] = f2bf((cg <= rg) ? accp[mm][i] : 0.f);
    }
  __syncthreads();

  f32x4 acco[2][4];
  #pragma unroll
  for (int mm = 0; mm < 2; ++mm)
    #pragma unroll
    for (int nn = 0; nn < 4; ++nn) { acco[mm][nn][0]=0.f; acco[mm][nn][1]=0.f; acco[mm][nn][2]=0.f; acco[mm][nn][3]=0.f; }

  #pragma unroll
  for (int t4 = 0; t4 < 2; ++t4) {
    bf16x8 ap[2];
    #pragma unroll
    for (int mm = 0; mm < 2; ++mm) {
      const int r = wr*32 + mm*16 + l15;
      ap[mm] = *(const bf16x8*)&SL[r*64 + ((t4*32 + lq*8) ^ key15)];
    }
    #pragma unroll
    for (int nn = 0; nn < 4; ++nn) {
      const int dv = wc*64 + nn*16 + l15;
      const bf16x8 bv = *(const bf16x8*)&SL[4096 + dv*64 + ((t4*32 + lq*8) ^ key15)];
      acco[0][nn] = __builtin_amdgcn_mfma_f32_16x16x32_bf16(ap[0], bv, acco[0][nn], 0, 0, 0);
      acco[1][nn] = __builtin_amdgcn_mfma_f32_16x16x32_bf16(ap[1], bv, acco[1][nn], 0, 0, 0);
    }
  }
  #pragma unroll
  for (int k4 = 0; k4 < 4; ++k4) {
    const int ch = k4 >> 1, k0c = (k4 & 1) * 32;
    #pragma unroll
    for (int nn = 0; nn < 4; ++nn) {
      const int dv = wc*64 + nn*16 + l15;
      const bf16x8 bs = *(const bf16x8*)&SL[20480 + ch*16384 + dv*64 + ((k0c + lq*8) ^ key15)];
      acco[0][nn] = __builtin_amdgcn_mfma_f32_16x16x32_bf16(aq[0][k4], bs, acco[0][nn], 0, 0, 0);
      acco[1][nn] = __builtin_amdgcn_mfma_f32_16x16x32_bf16(aq[1][k4], bs, acco[1][nn], 0, 0, 0);
    }
  }

  #pragma unroll
  for (int mm = 0; mm < 2; ++mm) {
    float part[4];
    #pragma unroll
    for (int i = 0; i < 4; ++i) {
      float s = 0.f;
      #pragma unroll
      for (int nn = 0; nn < 4; ++nn) s += acco[mm][nn][i]*acco[mm][nn][i];
      s += __shfl_xor(s, 1); s += __shfl_xor(s, 2); s += __shfl_xor(s, 4); s += __shfl_xor(s, 8);
      part[i] = s;
    }
    if (l15 == 0) {
      #pragma unroll
      for (int i = 0; i < 4; ++i)
        atomicAdd(&ssq[wr*32 + mm*16 + lq*4 + i], part[i]);
    }
  }
  __syncthreads();

  #pragma unroll
  for (int mm = 0; mm < 2; ++mm)
    #pragma unroll
    for (int i = 0; i < 4; ++i) {
      const int rg = wr*32 + mm*16 + lq*4 + i;
      const float rs = rsqrtf(ssq[rg] * (1.f/256.f) + 1e-5f);
      const size_t token = tok0 + rg;
      #pragma unroll
      for (int nn = 0; nn < 4; ++nn) {
        const int dv = wc*64 + nn*16 + l15;
        const float gf = bf2f(proj[token*3584 + 2048 + h*256 + dv]);
        const float swv = gf * __builtin_amdgcn_rcpf(1.f + __builtin_amdgcn_exp2f(-1.44269504f*gf));
        og[token*1024 + h*256 + dv] = f2bf(acco[mm][nn][i] * rs * gnw[dv] * swv);
      }
    }
}

extern "C" void kernel_launch(void* const* d_in, const int* in_sizes, int n_in,
                              void* d_out, int out_size, void* d_ws, size_t ws_size,
                              hipStream_t stream)
{
  (void)in_sizes; (void)n_in; (void)out_size; (void)ws_size;
  const float* x    = (const float*)d_in[0];
  const float* ln1g = (const float*)d_in[1];
  const float* ln1b = (const float*)d_in[2];
  const float* Wq   = (const float*)d_in[3];
  const float* Wk   = (const float*)d_in[4];
  const float* Wv   = (const float*)d_in[5];
  const float* Wg   = (const float*)d_in[6];
  const float* Wgk1 = (const float*)d_in[7];
  const float* Wgk2 = (const float*)d_in[8];
  const float* bgk  = (const float*)d_in[9];
  const float* gnw  = (const float*)d_in[10];
  const float* Wo   = (const float*)d_in[11];
  const float* ln2g = (const float*)d_in[12];
  const float* ln2b = (const float*)d_in[13];
  const float* W1   = (const float*)d_in[14];
  const float* b1   = (const float*)d_in[15];
  const float* W2   = (const float*)d_in[16];
  const float* b2   = (const float*)d_in[17];
  float* out = (float*)d_out;
  char* ws = (char*)d_ws;

  u16t*  XN   = (u16t*)(ws + 0);
  u16t*  KTT  = (u16t*)(ws + 0);
  u16t*  OG   = (u16t*)(ws + 0);
  u16t*  WPT  = (u16t*)(ws + 33554432);
  u16t*  WOT  = (u16t*)(ws + 40894464);
  u16t*  W1T  = (u16t*)(ws + 42991616);
  u16t*  W2T  = (u16t*)(ws + 51380224);
  u16t*  PROJ = (u16t*)(ws + 59768832);
  u16t*  QT   = (u16t*)(ws + 177209344);
  u16t*  KT   = (u16t*)(ws + 193986560);
  float* EAC  = (float*)(ws + 210763776);
  u16t*  VT   = (u16t*)(ws + 211288064);
  u16t*  H2   = (u16t*)(ws + 211288064);
  u16t*  HID  = PROJ;
  u16t*  SST  = (u16t*)d_out;

  k_transpose_multi<<<12288, dim3(32,8), 0, stream>>>(Wq, Wk, Wv, Wg, Wo, W1, W2, WPT, WOT, W1T, W2T);
  k_wgk<<<2048, 256, 0, stream>>>(Wgk1, Wgk2, WPT + (size_t)3072*1024);

  k_layernorm<<<16384, 256, 0, stream>>>(x, ln1g, ln1b, XN);
  gemm256<0><<<dim3(14,64), 1024, 0, stream>>>(XN, WPT, 3584, 1024, nullptr, PROJ, nullptr, nullptr);
  k_scanprep<<<1024, 128, 0, stream>>>(PROJ, bgk, QT, KT, EAC);
  k_vtrans<<<dim3(64,12,32), dim3(32,8), 0, stream>>>(PROJ, KT, VT, KTT);
  k_seqstate<<<256, 512, 0, stream>>>(KTT, VT, EAC, SST);
  k_attn_out<<<1024, 512, 0, stream>>>(QT, KT, VT, SST, PROJ, gnw, OG);
  gemm256<1><<<dim3(4,64),  1024, 0, stream>>>(OG, WOT, 1024, 1024, out, nullptr, x, nullptr);   // x1 = o@Wo + x
  k_layernorm<<<16384, 256, 0, stream>>>(out, ln2g, ln2b, H2);
  gemm256<2><<<dim3(16,64), 1024, 0, stream>>>(H2, W1T, 4096, 1024, nullptr, HID, nullptr, b1);  // gelu(h@W1+b1)
  gemm256<3><<<dim3(4,64),  1024, 0, stream>>>(HID, W2T, 1024, 4096, out, nullptr, out, b2);     // out = x1 + hid@W2 + b2
}